// Round 1
// baseline (381.678 us; speedup 1.0000x reference)
//
#include <hip/hip_runtime.h>

// Fused SNN forward for MI355X (gfx950).
// One block (256 threads) per image. Each thread owns up to 6 pool units
// (4 conv cells each). conv output + mem1 + pre-scaled fc weights live in
// registers across all 16 timesteps. Per timestep: LIF-1 update + per-unit
// spike count -> 10 weighted partials -> wave shfl_xor reduce -> LDS
// cross-wave reduce -> threads 0..9 run LIF-2 and accumulate spike counts.

__global__ __launch_bounds__(256) void snn_fused_kernel(
    const float* __restrict__ x,       // [4096, 1, 28, 28]
    const float* __restrict__ conv_w,  // [8, 1, 3, 3]
    const float* __restrict__ fc_w,    // [10, 1352]
    float* __restrict__ out)           // [4096, 10]
{
    const int b    = blockIdx.x;
    const int tid  = threadIdx.x;
    const int lane = tid & 63;
    const int wid  = tid >> 6;

    __shared__ float sx[784];    // 28x28 image
    __shared__ float scw[72];    // 8x3x3 conv weights
    __shared__ float sred[4][10];

    // ---- stage image + conv weights into LDS ----
    {
        const float4* xg  = reinterpret_cast<const float4*>(x + (size_t)b * 784);
        float4*       sx4 = reinterpret_cast<float4*>(sx);
        if (tid < 196) sx4[tid] = xg[tid];
        if (tid < 72)  scw[tid] = conv_w[tid];
    }
    __syncthreads();

    // ---- per-thread state: 6 pool units x 4 cells ----
    float cur[6][4];   // conv output (constant over time)
    float mem[6][4];   // LIF-1 membrane
    float wl[6][10];   // 0.25 * fc_w[o][unit]  (exact scale)

    #pragma unroll
    for (int i = 0; i < 6; ++i) {
        const int u     = tid + 256 * i;
        const bool valid = (u < 1352);
        const int uu  = valid ? u : 0;
        const int k   = uu / 169;          // channel
        const int rem = uu - k * 169;
        const int pr  = rem / 13;          // pool row
        const int pc  = rem - pr * 13;     // pool col

        // conv weights for this channel -> regs
        float cw[9];
        #pragma unroll
        for (int q = 0; q < 9; ++q) cw[q] = scw[k * 9 + q];

        // 4x4 input patch covering the 2x2 cell block -> regs
        float xr[4][4];
        #pragma unroll
        for (int r = 0; r < 4; ++r)
            #pragma unroll
            for (int c = 0; c < 4; ++c)
                xr[r][c] = sx[(2 * pr + r) * 28 + (2 * pc + c)];

        #pragma unroll
        for (int dr = 0; dr < 2; ++dr)
            #pragma unroll
            for (int dc = 0; dc < 2; ++dc) {
                float acc = 0.0f;
                #pragma unroll
                for (int ki = 0; ki < 3; ++ki)
                    #pragma unroll
                    for (int kj = 0; kj < 3; ++kj)
                        acc += xr[dr + ki][dc + kj] * cw[ki * 3 + kj];
                cur[i][dr * 2 + dc] = valid ? acc : 0.0f;
                mem[i][dr * 2 + dc] = 0.0f;
            }

        #pragma unroll
        for (int o = 0; o < 10; ++o)
            wl[i][o] = valid ? 0.25f * fc_w[o * 1352 + uu] : 0.0f;
    }

    float mem2 = 0.0f;
    float cnt2 = 0.0f;

    // ---- 16 timesteps ----
    for (int t = 0; t < 16; ++t) {
        float partial[10];
        #pragma unroll
        for (int o = 0; o < 10; ++o) partial[o] = 0.0f;

        #pragma unroll
        for (int i = 0; i < 6; ++i) {
            float fcnt = 0.0f;
            #pragma unroll
            for (int j = 0; j < 4; ++j) {
                float m  = 0.5f * mem[i][j] + cur[i][j];   // 0.5x exact
                float sp = (m > 1.0f) ? 1.0f : 0.0f;       // spike
                m -= sp;                                    // subtract-reset
                fcnt += sp;
                mem[i][j] = m;
            }
            #pragma unroll
            for (int o = 0; o < 10; ++o)
                partial[o] += wl[i][o] * fcnt;
        }

        // wave-level butterfly reduce (64 lanes), then cross-wave via LDS
        #pragma unroll
        for (int o = 0; o < 10; ++o) {
            float v = partial[o];
            v += __shfl_xor(v, 32);
            v += __shfl_xor(v, 16);
            v += __shfl_xor(v, 8);
            v += __shfl_xor(v, 4);
            v += __shfl_xor(v, 2);
            v += __shfl_xor(v, 1);
            if (lane == 0) sred[wid][o] = v;
        }
        __syncthreads();

        if (tid < 10) {
            const float c2 = sred[0][tid] + sred[1][tid] + sred[2][tid] + sred[3][tid];
            float m2 = 0.5f * mem2 + c2;
            const float sp = (m2 > 1.0f) ? 1.0f : 0.0f;
            m2 -= sp;
            cnt2 += sp;
            mem2 = m2;
        }
        __syncthreads();
    }

    if (tid < 10) out[(size_t)b * 10 + tid] = cnt2;
}

extern "C" void kernel_launch(void* const* d_in, const int* in_sizes, int n_in,
                              void* d_out, int out_size, void* d_ws, size_t ws_size,
                              hipStream_t stream) {
    const float* x      = (const float*)d_in[0];  // 4096*784
    const float* conv_w = (const float*)d_in[1];  // 72
    const float* fc_w   = (const float*)d_in[2];  // 13520
    float* out          = (float*)d_out;          // 40960

    const int B = in_sizes[0] / 784;              // 4096
    snn_fused_kernel<<<B, 256, 0, stream>>>(x, conv_w, fc_w, out);
}

// Round 2
// 139.705 us; speedup vs baseline: 2.7320x; 2.7320x over previous
//
#include <hip/hip_runtime.h>

// Fused SNN forward for MI355X (gfx950) — round 2.
// One block (256 threads) per image. Per-thread: 6 pool units x 4 cells,
// conv output + mem1 + 0.25*fc_w in registers across all 16 timesteps.
//
// Round-2 restructure: layer-1 dynamics are independent of layer 2, so the
// per-timestep block reduction + LIF-2 is DEFERRED. The 16-step loop runs
// with ZERO barriers: LIF + 60 FMA + 2-level shfl (xor32, xor16) -> 16
// four-lane-group partials per wave per t written to padded LDS. One barrier,
// 160-thread final reduce (64 adds each), one barrier, 10-lane LIF-2 scan.

#define LDSP 161  // padded row stride (dwords): bank = s*161 % 32 = s -> conflict-free

__global__ __launch_bounds__(256) void snn_fused_kernel(
    const float* __restrict__ x,       // [4096, 1, 28, 28]
    const float* __restrict__ conv_w,  // [8, 1, 3, 3]
    const float* __restrict__ fc_w,    // [10, 1352]
    float* __restrict__ out)           // [4096, 10]
{
    const int b    = blockIdx.x;
    const int tid  = threadIdx.x;
    const int lane = tid & 63;
    const int wid  = tid >> 6;

    __shared__ float sx[784];           // 28x28 image
    __shared__ float scw[72];           // 8x3x3 conv weights
    __shared__ float sred[64 * LDSP];   // [wid*16+s][t*10+o], s = 4-lane group id
    __shared__ float scur2[160];        // [t][o]

    // ---- stage image + conv weights into LDS ----
    {
        const float4* xg  = reinterpret_cast<const float4*>(x + (size_t)b * 784);
        float4*       sx4 = reinterpret_cast<float4*>(sx);
        if (tid < 196) sx4[tid] = xg[tid];
        if (tid < 72)  scw[tid] = conv_w[tid];
    }
    __syncthreads();

    // ---- per-thread state: 6 pool units x 4 cells ----
    float cur[6][4];   // conv output (constant over time)
    float mem[6][4];   // LIF-1 membrane
    float wl[6][10];   // 0.25 * fc_w[o][unit]

    #pragma unroll
    for (int i = 0; i < 6; ++i) {
        const int u      = tid + 256 * i;
        const bool valid = (u < 1352);
        const int uu  = valid ? u : 0;
        const int k   = uu / 169;          // channel
        const int rem = uu - k * 169;
        const int pr  = rem / 13;          // pool row
        const int pc  = rem - pr * 13;     // pool col

        float cw[9];
        #pragma unroll
        for (int q = 0; q < 9; ++q) cw[q] = scw[k * 9 + q];

        float xr[4][4];
        #pragma unroll
        for (int r = 0; r < 4; ++r)
            #pragma unroll
            for (int c = 0; c < 4; ++c)
                xr[r][c] = sx[(2 * pr + r) * 28 + (2 * pc + c)];

        #pragma unroll
        for (int dr = 0; dr < 2; ++dr)
            #pragma unroll
            for (int dc = 0; dc < 2; ++dc) {
                float acc = 0.0f;
                #pragma unroll
                for (int ki = 0; ki < 3; ++ki)
                    #pragma unroll
                    for (int kj = 0; kj < 3; ++kj)
                        acc += xr[dr + ki][dc + kj] * cw[ki * 3 + kj];
                cur[i][dr * 2 + dc] = valid ? acc : 0.0f;
                mem[i][dr * 2 + dc] = 0.0f;
            }

        #pragma unroll
        for (int o = 0; o < 10; ++o)
            wl[i][o] = valid ? 0.25f * fc_w[o * 1352 + uu] : 0.0f;
    }

    // ---- 16 timesteps, NO barriers ----
    for (int t = 0; t < 16; ++t) {
        float v[10];
        #pragma unroll
        for (int o = 0; o < 10; ++o) v[o] = 0.0f;

        #pragma unroll
        for (int i = 0; i < 6; ++i) {
            int c = 0;
            #pragma unroll
            for (int j = 0; j < 4; ++j) {
                float m  = __builtin_fmaf(0.5f, mem[i][j], cur[i][j]);
                float ms = m - 1.0f;                 // spike iff ms > 0 (== mem-THR > 0)
                bool  sp = ms > 0.0f;
                mem[i][j] = sp ? ms : m;             // subtract-reset
                c += sp;
            }
            const float fc = (float)c;               // 0..4 exact
            #pragma unroll
            for (int o = 0; o < 10; ++o)
                v[o] = __builtin_fmaf(wl[i][o], fc, v[o]);
        }

        // 2-level butterfly: lane l ends with sum over {l, l^16, l^32, l^48}
        #pragma unroll
        for (int o = 0; o < 10; ++o) {
            float a = v[o];
            a += __shfl_xor(a, 32);
            a += __shfl_xor(a, 16);
            v[o] = a;
        }
        // lanes 0..15 hold the 16 distinct 4-lane-group sums of this wave
        if (lane < 16) {
            float* base = &sred[(wid * 16 + lane) * LDSP + t * 10];
            #pragma unroll
            for (int o = 0; o < 10; ++o) base[o] = v[o];
        }
    }
    __syncthreads();

    // ---- final reduce: 160 threads, one (t,o) each, 64 partials ----
    if (tid < 160) {
        const int t = tid / 10;
        const int o = tid - t * 10;
        float sum = 0.0f;
        #pragma unroll
        for (int g = 0; g < 64; ++g)
            sum += sred[g * LDSP + t * 10 + o];
        scur2[t * 10 + o] = sum;
    }
    __syncthreads();

    // ---- LIF-2 scan over 16 timesteps, 10 lanes ----
    if (tid < 10) {
        float m2 = 0.0f, cnt = 0.0f;
        #pragma unroll
        for (int t = 0; t < 16; ++t) {
            m2 = __builtin_fmaf(0.5f, m2, scur2[t * 10 + tid]);
            float ms = m2 - 1.0f;
            bool  sp = ms > 0.0f;
            m2  = sp ? ms : m2;
            cnt += sp ? 1.0f : 0.0f;
        }
        out[(size_t)b * 10 + tid] = cnt;
    }
}

extern "C" void kernel_launch(void* const* d_in, const int* in_sizes, int n_in,
                              void* d_out, int out_size, void* d_ws, size_t ws_size,
                              hipStream_t stream) {
    const float* x      = (const float*)d_in[0];  // 4096*784
    const float* conv_w = (const float*)d_in[1];  // 72
    const float* fc_w   = (const float*)d_in[2];  // 13520
    float* out          = (float*)d_out;          // 40960

    const int B = in_sizes[0] / 784;              // 4096
    snn_fused_kernel<<<B, 256, 0, stream>>>(x, conv_w, fc_w, out);
}